// Round 1
// baseline (311.941 us; speedup 1.0000x reference)
//
#include <hip/hip_runtime.h>
#include <hip/hip_bf16.h>

typedef _Float16 half8 __attribute__((ext_vector_type(8)));
typedef float floatx4 __attribute__((ext_vector_type(4)));

#define NEDGE 200000
#define BM 128
#define NBLK ((NEDGE + BM - 1) / BM) /* 1563 */

__device__ _Float16 g_w1[256 * 256]; // [n][k] fp16 (transposed W1)
__device__ _Float16 g_w2[256 * 256]; // [n][k] fp16 (transposed W2)

__global__ void prep_weights(const float* __restrict__ W1, const float* __restrict__ W2) {
    int t = blockIdx.x * 256 + threadIdx.x;   // 0..65535, t = k*256 + n
    int k = t >> 8, n = t & 255;
    g_w1[n * 256 + k] = (_Float16)W1[t];
    g_w2[n * 256 + k] = (_Float16)W2[t];
}

__global__ __launch_bounds__(256, 2) void fused_decoder(
    const float* __restrict__ x,
    const int* __restrict__ psrc, const int* __restrict__ pdst,
    const int* __restrict__ nsrc, const int* __restrict__ ndst,
    const float* __restrict__ b1, const float* __restrict__ b2,
    const float* __restrict__ W3, const float* __restrict__ b3,
    float* __restrict__ out)
{
    __shared__ _Float16 eT[BM * 256];   // 64KB, XOR-swizzled rows

    const int bid  = blockIdx.x;
    const bool posg = bid < NBLK;
    const int tb   = posg ? bid : bid - NBLK;
    const int base = tb * BM;
    const int rows = min(BM, NEDGE - base);
    const int* __restrict__ srcI = posg ? psrc : nsrc;
    const int* __restrict__ dstI = posg ? pdst : ndst;
    const int obase = posg ? 0 : NEDGE;

    const int tid  = threadIdx.x;
    const int lane = tid & 63;
    const int wid  = tid >> 6;     // 0..3, wave owns cols [wid*64, wid*64+64)
    const int n0   = wid * 64;
    const int l15  = lane & 15;
    const int lhi  = lane >> 4;    // 0..3

    // ---------------- gather + elementwise product -> eT (fp16) ----------------
    {
        const int row = tid >> 1;
        const int c0  = (tid & 1) * 128;
        if (row < rows) {
            const long s = srcI[base + row];
            const long d = dstI[base + row];
            const float* __restrict__ xs = x + s * 256;
            const float* __restrict__ xd = x + d * 256;
            const unsigned swzrow = (unsigned)((row & 7) << 4);
            #pragma unroll
            for (int c = 0; c < 128; c += 8) {
                floatx4 a0 = *(const floatx4*)(xs + c0 + c);
                floatx4 a1 = *(const floatx4*)(xs + c0 + c + 4);
                floatx4 d0 = *(const floatx4*)(xd + c0 + c);
                floatx4 d1 = *(const floatx4*)(xd + c0 + c + 4);
                half8 h;
                h[0] = (_Float16)(a0[0] * d0[0]);
                h[1] = (_Float16)(a0[1] * d0[1]);
                h[2] = (_Float16)(a0[2] * d0[2]);
                h[3] = (_Float16)(a0[3] * d0[3]);
                h[4] = (_Float16)(a1[0] * d1[0]);
                h[5] = (_Float16)(a1[1] * d1[1]);
                h[6] = (_Float16)(a1[2] * d1[2]);
                h[7] = (_Float16)(a1[3] * d1[3]);
                unsigned addr = ((unsigned)(row * 512 + (c0 + c) * 2)) ^ swzrow;
                *(half8*)((char*)eT + addr) = h;
            }
        }
    }
    __syncthreads();

    const unsigned alin = (unsigned)(l15 * 512 + lhi * 16); // A-frag lane base
    const unsigned aswz = (unsigned)((l15 & 7) << 4);

    floatx4 acc[8][4];

    // ---------------- layer 1: h1 = relu(e @ W1 + b1) ----------------
    #pragma unroll
    for (int mi = 0; mi < 8; ++mi)
        #pragma unroll
        for (int ni = 0; ni < 4; ++ni)
            acc[mi][ni] = (floatx4){0.f, 0.f, 0.f, 0.f};
    {
        const _Float16* __restrict__ wb = g_w1 + (n0 + l15) * 256 + lhi * 8;
        half8 bcur[4], bnext[4];
        #pragma unroll
        for (int ni = 0; ni < 4; ++ni) bcur[ni] = *(const half8*)(wb + ni * 4096);
        #pragma unroll
        for (int kk = 0; kk < 8; ++kk) {
            if (kk < 7) {
                #pragma unroll
                for (int ni = 0; ni < 4; ++ni)
                    bnext[ni] = *(const half8*)(wb + ni * 4096 + (kk + 1) * 32);
            }
            #pragma unroll
            for (int mi = 0; mi < 8; ++mi) {
                half8 a = *(const half8*)((char*)eT + ((alin + mi * 8192 + kk * 64) ^ aswz));
                #pragma unroll
                for (int ni = 0; ni < 4; ++ni)
                    acc[mi][ni] = __builtin_amdgcn_mfma_f32_16x16x32_f16(a, bcur[ni], acc[mi][ni], 0, 0, 0);
            }
            #pragma unroll
            for (int ni = 0; ni < 4; ++ni) bcur[ni] = bnext[ni];
        }
    }
    // bias + relu, write h1 back to eT (fp16, same swizzle)
    {
        float b1v[4];
        #pragma unroll
        for (int ni = 0; ni < 4; ++ni) b1v[ni] = b1[n0 + ni * 16 + l15];
        __syncthreads();   // all layer-1 A reads complete before overwrite
        #pragma unroll
        for (int mi = 0; mi < 8; ++mi)
            #pragma unroll
            for (int ni = 0; ni < 4; ++ni)
                #pragma unroll
                for (int r = 0; r < 4; ++r) {
                    float h = fmaxf(acc[mi][ni][r] + b1v[ni], 0.f);
                    int row = mi * 16 + lhi * 4 + r;
                    int col = n0 + ni * 16 + l15;
                    unsigned addr = ((unsigned)(row * 512 + col * 2)) ^ ((unsigned)((row & 7) << 4));
                    *(_Float16*)((char*)eT + addr) = (_Float16)h;
                }
        __syncthreads();
    }

    // ---------------- layer 2: h2 = relu(h1 @ W2 + b2) ----------------
    #pragma unroll
    for (int mi = 0; mi < 8; ++mi)
        #pragma unroll
        for (int ni = 0; ni < 4; ++ni)
            acc[mi][ni] = (floatx4){0.f, 0.f, 0.f, 0.f};
    {
        const _Float16* __restrict__ wb = g_w2 + (n0 + l15) * 256 + lhi * 8;
        half8 bcur[4], bnext[4];
        #pragma unroll
        for (int ni = 0; ni < 4; ++ni) bcur[ni] = *(const half8*)(wb + ni * 4096);
        #pragma unroll
        for (int kk = 0; kk < 8; ++kk) {
            if (kk < 7) {
                #pragma unroll
                for (int ni = 0; ni < 4; ++ni)
                    bnext[ni] = *(const half8*)(wb + ni * 4096 + (kk + 1) * 32);
            }
            #pragma unroll
            for (int mi = 0; mi < 8; ++mi) {
                half8 a = *(const half8*)((char*)eT + ((alin + mi * 8192 + kk * 64) ^ aswz));
                #pragma unroll
                for (int ni = 0; ni < 4; ++ni)
                    acc[mi][ni] = __builtin_amdgcn_mfma_f32_16x16x32_f16(a, bcur[ni], acc[mi][ni], 0, 0, 0);
            }
            #pragma unroll
            for (int ni = 0; ni < 4; ++ni) bcur[ni] = bnext[ni];
        }
    }

    // ---------------- layer 3: out = relu(h2) @ W3 + b3 (bias b2 folded here) ----------------
    float w3v[4], b2v[4];
    #pragma unroll
    for (int ni = 0; ni < 4; ++ni) {
        b2v[ni] = b2[n0 + ni * 16 + l15];
        w3v[ni] = W3[n0 + ni * 16 + l15];
    }
    __syncthreads();               // all layer-2 A reads done; reuse eT as float partials
    float* part = (float*)eT;      // [row][wave] = [128][4] f32
    #pragma unroll
    for (int mi = 0; mi < 8; ++mi)
        #pragma unroll
        for (int r = 0; r < 4; ++r) {
            float s = 0.f;
            #pragma unroll
            for (int ni = 0; ni < 4; ++ni)
                s += fmaxf(acc[mi][ni][r] + b2v[ni], 0.f) * w3v[ni];
            s += __shfl_xor(s, 1);
            s += __shfl_xor(s, 2);
            s += __shfl_xor(s, 4);
            s += __shfl_xor(s, 8);
            if (l15 == 0) {
                int row = mi * 16 + lhi * 4 + r;
                part[row * 4 + wid] = s;
            }
        }
    __syncthreads();
    if (tid < rows) {
        floatx4 p = *(const floatx4*)(part + tid * 4);
        out[obase + base + tid] = p[0] + p[1] + p[2] + p[3] + b3[0];
    }
}

extern "C" void kernel_launch(void* const* d_in, const int* in_sizes, int n_in,
                              void* d_out, int out_size, void* d_ws, size_t ws_size,
                              hipStream_t stream) {
    const float* x    = (const float*)d_in[0];
    const int* psrc   = (const int*)d_in[1];
    const int* pdst   = (const int*)d_in[2];
    const int* nsrc   = (const int*)d_in[3];
    const int* ndst   = (const int*)d_in[4];
    const float* W1   = (const float*)d_in[5];
    const float* b1   = (const float*)d_in[6];
    const float* W2   = (const float*)d_in[7];
    const float* b2   = (const float*)d_in[8];
    const float* W3   = (const float*)d_in[9];
    const float* b3   = (const float*)d_in[10];

    prep_weights<<<256, 256, 0, stream>>>(W1, W2);
    fused_decoder<<<2 * NBLK, 256, 0, stream>>>(x, psrc, pdst, nsrc, ndst,
                                                b1, b2, W3, b3, (float*)d_out);
}